// Round 1
// baseline (447.396 us; speedup 1.0000x reference)
//
#include <hip/hip_runtime.h>

// Problem constants (match reference)
#define C_BINS 9
#define H_IN 180
#define W_IN 240
#define IMG 640
#define NEV 250000
#define BATCH 8
#define NEG_SLOPE 0.1f
#define HW (H_IN * W_IN)                         // 43200
#define NV (2 * C_BINS * HW * BATCH)             // 6,220,800 voxels
#define TN 8192                                  // table intervals (TN+1 nodes over [-1,1])

// workspace layout (bytes)
#define WS_BMAX_OFF   0            // 8 x u32 (float bits)
#define WS_TABLE_OFF  128          // 8193 x f32
#define WS_VOX_OFF    65536        // 6,220,800 x f32

// ---------------- kernel A: per-batch max of t ----------------
__global__ void bmax_kernel(const float* __restrict__ ev, unsigned int* __restrict__ bmax) {
    __shared__ unsigned int sm[BATCH];
    int tid = threadIdx.x;
    if (tid < BATCH) sm[tid] = 0u;
    __syncthreads();
    int i = blockIdx.x * blockDim.x + tid;
    if (i < NEV) {
        float t = ev[i * 5 + 2];          // t > 0 always -> int ordering == float ordering
        int b = (int)ev[i * 5 + 4];
        atomicMax(&sm[b], __float_as_uint(t));
    }
    __syncthreads();
    if (tid < BATCH) atomicMax(&bmax[tid], sm[tid]);
}

// ---------------- kernel B: tabulate g(s) = value_layer(s) ----------------
// one block of 128 threads handles 8 consecutive s-nodes; W2 staged in LDS
__global__ __launch_bounds__(128) void table_kernel(
        const float* __restrict__ W1, const float* __restrict__ b1,
        const float* __restrict__ W2, const float* __restrict__ b2,
        const float* __restrict__ W3, const float* __restrict__ b3,
        float* __restrict__ table) {
    __shared__ float W2s[100 * 100];
    __shared__ float h1s[100];
    __shared__ float red[128];
    int tid = threadIdx.x;
    for (int i = tid; i < 100 * 100; i += 128) W2s[i] = W2[i];
    float w1v = 0.f, b1v = 0.f, b2v = 0.f, w3v = 0.f;
    if (tid < 100) { w1v = W1[tid]; b1v = b1[tid]; b2v = b2[tid]; w3v = W3[tid]; }
    float b3v = b3[0];

    for (int r = 0; r < 8; ++r) {
        int sidx = blockIdx.x * 8 + r;
        if (sidx > TN) break;
        float s = -1.f + 2.f * (float)sidx / (float)TN;
        __syncthreads();
        if (tid < 100) {
            float h = fmaf(s, w1v, b1v);
            h1s[tid] = h > 0.f ? h : NEG_SLOPE * h;
        }
        __syncthreads();
        float acc = 0.f;
        if (tid < 100) {
            #pragma unroll 4
            for (int j = 0; j < 100; ++j) acc = fmaf(h1s[j], W2s[j * 100 + tid], acc);
            acc += b2v;
            acc = acc > 0.f ? acc : NEG_SLOPE * acc;
            acc *= w3v;
        }
        red[tid] = acc;
        __syncthreads();
        for (int off = 64; off > 0; off >>= 1) {
            if (tid < off) red[tid] += red[tid + off];
            __syncthreads();
        }
        if (tid == 0) table[sidx] = red[0] + b3v;
    }
}

// ---------------- kernel C: scatter events into voxel grid ----------------
__global__ void scatter_kernel(const float* __restrict__ ev,
                               const float* __restrict__ bmax,
                               const float* __restrict__ table,
                               float* __restrict__ vox) {
    int i = blockIdx.x * blockDim.x + threadIdx.x;
    if (i >= NEV) return;
    float x = ev[i * 5 + 0];
    float y = ev[i * 5 + 1];
    float t = ev[i * 5 + 2];
    float p = ev[i * 5 + 3];
    int   b = (int)ev[i * 5 + 4];
    float tn = t / bmax[b];
    int base = (int)x + W_IN * (int)y + HW * C_BINS * (int)p + HW * C_BINS * 2 * b;
    #pragma unroll
    for (int bin = 0; bin < C_BINS; ++bin) {
        float s = tn - (float)bin * 0.125f;       // i/(C-1) = i/8, exact
        float u = (s + 1.f) * (0.5f * (float)TN); // node index in [0, TN]
        int k = (int)floorf(u);
        k = max(0, min(k, TN - 1));
        float f = u - (float)k;
        float t0 = table[k], t1 = table[k + 1];
        float g = fmaf(t1 - t0, f, t0);
        int idx = base + HW * bin;
        idx = max(0, min(idx, NV - 1));
        atomicAdd(&vox[idx], tn * g);
    }
}

// ---------------- kernel D: letterbox fill + bilinear resize ----------------
// one thread per 4 consecutive output pixels (float4 store)
__global__ void out_kernel(const float* __restrict__ vox, float* __restrict__ out) {
    int gid = blockIdx.x * blockDim.x + threadIdx.x;   // 4-pixel group
    // layout: ((bc * 640) + oy) * 640 + ox ; 160 groups per row
    int gx   = gid % 160;
    int rest = gid / 160;
    int oy   = rest % IMG;
    int bc   = rest / IMG;                              // 0..143 = b*18 + ch
    float4 v;
    if (oy < 80 || oy >= 560) {
        v = make_float4(114.f, 114.f, 114.f, 114.f);
    } else {
        int ry = oy - 80;                               // 0..479
        float sy = fmaf((float)ry + 0.5f, 0.375f, -0.5f);
        int y0 = (int)floorf(sy);
        float wy = sy - (float)y0;
        int y1 = min(y0 + 1, H_IN - 1);
        y0 = max(y0, 0);
        const float* r0 = vox + bc * HW + y0 * W_IN;
        const float* r1 = vox + bc * HW + y1 * W_IN;
        float res[4];
        #pragma unroll
        for (int q = 0; q < 4; ++q) {
            int ox = gx * 4 + q;
            float sx = fmaf((float)ox + 0.5f, 0.375f, -0.5f);
            int x0 = (int)floorf(sx);
            float wx = sx - (float)x0;
            int x1 = min(x0 + 1, W_IN - 1);
            x0 = max(x0, 0);
            float top = fmaf(r0[x1] - r0[x0], wx, r0[x0]);
            float bot = fmaf(r1[x1] - r1[x0], wx, r1[x0]);
            res[q] = fmaf(bot - top, wy, top);
        }
        v = make_float4(res[0], res[1], res[2], res[3]);
    }
    ((float4*)out)[gid] = v;
}

extern "C" void kernel_launch(void* const* d_in, const int* in_sizes, int n_in,
                              void* d_out, int out_size, void* d_ws, size_t ws_size,
                              hipStream_t stream) {
    const float* ev = (const float*)d_in[0];
    const float* W1 = (const float*)d_in[1];
    const float* b1 = (const float*)d_in[2];
    const float* W2 = (const float*)d_in[3];
    const float* b2 = (const float*)d_in[4];
    const float* W3 = (const float*)d_in[5];
    const float* b3 = (const float*)d_in[6];
    float* out = (float*)d_out;

    char* ws = (char*)d_ws;
    unsigned int* bmax_u = (unsigned int*)(ws + WS_BMAX_OFF);
    float*        bmax_f = (float*)(ws + WS_BMAX_OFF);
    float*        table  = (float*)(ws + WS_TABLE_OFF);
    float*        vox    = (float*)(ws + WS_VOX_OFF);

    // zero bmax + vox (ws is poisoned 0xAA before every timed launch)
    hipMemsetAsync(bmax_u, 0, BATCH * sizeof(unsigned int), stream);
    hipMemsetAsync(vox, 0, (size_t)NV * sizeof(float), stream);

    bmax_kernel<<<(NEV + 255) / 256, 256, 0, stream>>>(ev, bmax_u);
    table_kernel<<<(TN + 1 + 7) / 8, 128, 0, stream>>>(W1, b1, W2, b2, W3, b3, table);
    scatter_kernel<<<(NEV + 255) / 256, 256, 0, stream>>>(ev, bmax_f, table, vox);

    const int ngroups = (BATCH * 2 * C_BINS) * IMG * (IMG / 4);  // 14,745,600
    out_kernel<<<ngroups / 256, 256, 0, stream>>>(vox, out);
}

// Round 2
// 402.743 us; speedup vs baseline: 1.1109x; 1.1109x over previous
//
#include <hip/hip_runtime.h>

// Problem constants (match reference)
#define C_BINS 9
#define H_IN 180
#define W_IN 240
#define IMG 640
#define NEV 250000
#define BATCH 8
#define NEG_SLOPE 0.1f
#define HW (H_IN * W_IN)                         // 43200
#define NV (2 * C_BINS * HW * BATCH)             // 6,220,800 voxels
#define TN 8192                                  // table intervals (TN+1 nodes over [-1,1])

// workspace layout (bytes)
#define WS_BMAX_OFF   0            // 8 x u32 (float bits)
#define WS_TABLE_OFF  128          // 8193 x f32
#define WS_VOX_OFF    65536        // 6,220,800 x f32

// ---------------- kernel A: per-batch max of t ----------------
__global__ void bmax_kernel(const float* __restrict__ ev, unsigned int* __restrict__ bmax) {
    __shared__ unsigned int sm[BATCH];
    int tid = threadIdx.x;
    if (tid < BATCH) sm[tid] = 0u;
    __syncthreads();
    int i = blockIdx.x * blockDim.x + tid;
    if (i < NEV) {
        float t = ev[i * 5 + 2];          // t > 0 always -> int ordering == float ordering
        int b = (int)ev[i * 5 + 4];
        atomicMax(&sm[b], __float_as_uint(t));
    }
    __syncthreads();
    if (tid < BATCH) atomicMax(&bmax[tid], sm[tid]);
}

// ---------------- kernel B: tabulate g(s) = value_layer(s) ----------------
// one block of 128 threads handles 8 consecutive s-nodes; W2 staged in LDS
__global__ __launch_bounds__(128) void table_kernel(
        const float* __restrict__ W1, const float* __restrict__ b1,
        const float* __restrict__ W2, const float* __restrict__ b2,
        const float* __restrict__ W3, const float* __restrict__ b3,
        float* __restrict__ table) {
    __shared__ float W2s[100 * 100];
    __shared__ float h1s[100];
    __shared__ float red[128];
    int tid = threadIdx.x;
    for (int i = tid; i < 100 * 100; i += 128) W2s[i] = W2[i];
    float w1v = 0.f, b1v = 0.f, b2v = 0.f, w3v = 0.f;
    if (tid < 100) { w1v = W1[tid]; b1v = b1[tid]; b2v = b2[tid]; w3v = W3[tid]; }
    float b3v = b3[0];

    for (int r = 0; r < 8; ++r) {
        int sidx = blockIdx.x * 8 + r;
        if (sidx > TN) break;
        float s = -1.f + 2.f * (float)sidx / (float)TN;
        __syncthreads();
        if (tid < 100) {
            float h = fmaf(s, w1v, b1v);
            h1s[tid] = h > 0.f ? h : NEG_SLOPE * h;
        }
        __syncthreads();
        float acc = 0.f;
        if (tid < 100) {
            #pragma unroll 4
            for (int j = 0; j < 100; ++j) acc = fmaf(h1s[j], W2s[j * 100 + tid], acc);
            acc += b2v;
            acc = acc > 0.f ? acc : NEG_SLOPE * acc;
            acc *= w3v;
        }
        red[tid] = acc;
        __syncthreads();
        for (int off = 64; off > 0; off >>= 1) {
            if (tid < off) red[tid] += red[tid + off];
            __syncthreads();
        }
        if (tid == 0) table[sidx] = red[0] + b3v;
    }
}

// ---------------- kernel C: scatter events into voxel grid ----------------
__global__ void scatter_kernel(const float* __restrict__ ev,
                               const float* __restrict__ bmax,
                               const float* __restrict__ table,
                               float* __restrict__ vox) {
    int i = blockIdx.x * blockDim.x + threadIdx.x;
    if (i >= NEV) return;
    float x = ev[i * 5 + 0];
    float y = ev[i * 5 + 1];
    float t = ev[i * 5 + 2];
    float p = ev[i * 5 + 3];
    int   b = (int)ev[i * 5 + 4];
    float tn = t / bmax[b];
    int base = (int)x + W_IN * (int)y + HW * C_BINS * (int)p + HW * C_BINS * 2 * b;
    #pragma unroll
    for (int bin = 0; bin < C_BINS; ++bin) {
        float s = tn - (float)bin * 0.125f;       // i/(C-1) = i/8, exact
        float u = (s + 1.f) * (0.5f * (float)TN); // node index in [0, TN]
        int k = (int)floorf(u);
        k = max(0, min(k, TN - 1));
        float f = u - (float)k;
        float t0 = table[k], t1 = table[k + 1];
        float g = fmaf(t1 - t0, f, t0);
        int idx = base + HW * bin;
        idx = max(0, min(idx, NV - 1));
        atomicAdd(&vox[idx], tn * g);
    }
}

// ---------------- kernel D: letterbox fill + bilinear resize, LDS-staged ----
// one block per (plane, 8-output-row tile); stages the <=5 needed input rows
// in LDS via coalesced loads, then computes bilinear from LDS. Bar tiles
// (oy<80 / oy>=560) are tile-aligned -> uniform constant fill, no divergence.
__global__ __launch_bounds__(256) void out_kernel2(const float* __restrict__ vox,
                                                   float* __restrict__ out) {
    int bc = blockIdx.x / 80;          // 0..143 plane (b*18 + ch)
    int ty = blockIdx.x % 80;          // 8-row tile within the 640-row image
    int oy0 = ty * 8;
    int tid = threadIdx.x;
    float4* dst = (float4*)(out + ((size_t)bc * IMG + oy0) * IMG);

    if (ty < 10 || ty >= 70) {         // letterbox bars: oy0 in [0,72] or [560,632]
        float4 v = make_float4(114.f, 114.f, 114.f, 114.f);
        for (int g = tid; g < 1280; g += 256) dst[g] = v;
        return;
    }

    __shared__ float sm[5][W_IN];
    int ry0 = oy0 - 80;                                // 0..472
    float sy0 = fmaf((float)ry0 + 0.5f, 0.375f, -0.5f);
    int ybase = (int)floorf(sy0);                      // may be -1
    const float* plane = vox + (size_t)bc * HW;
    for (int idx = tid; idx < 5 * W_IN; idx += 256) {
        int r = idx / W_IN, c = idx - (idx / W_IN) * W_IN;
        int sr = min(max(ybase + r, 0), H_IN - 1);
        sm[r][c] = plane[sr * W_IN + c];
    }
    __syncthreads();

    for (int g = tid; g < 1280; g += 256) {            // 8 rows x 160 float4 groups
        int row = g / 160;
        int gx = g - row * 160;
        int ry = ry0 + row;
        float sy = fmaf((float)ry + 0.5f, 0.375f, -0.5f);
        int y0 = (int)floorf(sy);
        float wy = sy - (float)y0;
        int l1 = min(y0 + 1, H_IN - 1) - ybase;        // local LDS row indices, 0..4
        int l0 = max(y0, 0) - ybase;
        const float* r0 = sm[l0];
        const float* r1 = sm[l1];
        float res[4];
        #pragma unroll
        for (int q = 0; q < 4; ++q) {
            int ox = gx * 4 + q;
            float sx = fmaf((float)ox + 0.5f, 0.375f, -0.5f);
            int x0 = (int)floorf(sx);
            float wx = sx - (float)x0;
            int x1 = min(x0 + 1, W_IN - 1);
            x0 = max(x0, 0);
            float top = fmaf(r0[x1] - r0[x0], wx, r0[x0]);
            float bot = fmaf(r1[x1] - r1[x0], wx, r1[x0]);
            res[q] = fmaf(bot - top, wy, top);
        }
        dst[g] = make_float4(res[0], res[1], res[2], res[3]);
    }
}

extern "C" void kernel_launch(void* const* d_in, const int* in_sizes, int n_in,
                              void* d_out, int out_size, void* d_ws, size_t ws_size,
                              hipStream_t stream) {
    const float* ev = (const float*)d_in[0];
    const float* W1 = (const float*)d_in[1];
    const float* b1 = (const float*)d_in[2];
    const float* W2 = (const float*)d_in[3];
    const float* b2 = (const float*)d_in[4];
    const float* W3 = (const float*)d_in[5];
    const float* b3 = (const float*)d_in[6];
    float* out = (float*)d_out;

    char* ws = (char*)d_ws;
    unsigned int* bmax_u = (unsigned int*)(ws + WS_BMAX_OFF);
    float*        bmax_f = (float*)(ws + WS_BMAX_OFF);
    float*        table  = (float*)(ws + WS_TABLE_OFF);
    float*        vox    = (float*)(ws + WS_VOX_OFF);

    // zero bmax + vox (ws is poisoned 0xAA before every timed launch)
    hipMemsetAsync(bmax_u, 0, BATCH * sizeof(unsigned int), stream);
    hipMemsetAsync(vox, 0, (size_t)NV * sizeof(float), stream);

    bmax_kernel<<<(NEV + 255) / 256, 256, 0, stream>>>(ev, bmax_u);
    table_kernel<<<(TN + 1 + 7) / 8, 128, 0, stream>>>(W1, b1, W2, b2, W3, b3, table);
    scatter_kernel<<<(NEV + 255) / 256, 256, 0, stream>>>(ev, bmax_f, table, vox);

    out_kernel2<<<144 * 80, 256, 0, stream>>>(vox, out);
}

// Round 3
// 386.603 us; speedup vs baseline: 1.1573x; 1.0417x over previous
//
#include <hip/hip_runtime.h>

// Problem constants (match reference)
#define C_BINS 9
#define H_IN 180
#define W_IN 240
#define IMG 640
#define NEV 250000
#define BATCH 8
#define NEG_SLOPE 0.1f
#define HW (H_IN * W_IN)                         // 43200
#define NV (2 * C_BINS * HW * BATCH)             // 6,220,800 voxels
#define TN 2048                                  // table intervals (TN+1 nodes over [-1,1])

// workspace layout (bytes)
#define WS_BMAX_OFF   0            // 8 x i32 (float bits; signed-max trick, no init needed)
#define WS_TABLE_OFF  128          // (TN+1) x f32
#define WS_VOX_OFF    65536        // NV x f32 (16B aligned)

// ---------------- kernel A: fused prep ----------------
// Phase A: zero vox (float4, grid-stride)
// Phase B: per-batch max of t -> signed atomicMax on float bits.
//          0xAA poison = negative as i32; any positive float's bits win -> no memset.
// Phase C: block b computes table node b (one of TN+1), W2 read straight from L2.
__global__ __launch_bounds__(128) void prep_kernel(
        const float* __restrict__ ev,
        const float* __restrict__ W1, const float* __restrict__ b1,
        const float* __restrict__ W2, const float* __restrict__ b2,
        const float* __restrict__ W3, const float* __restrict__ b3,
        int* __restrict__ bmax_i, float* __restrict__ table,
        float4* __restrict__ vox4) {
    int blk = blockIdx.x, tid = threadIdx.x;
    int gtid = blk * 128 + tid;
    int gstride = gridDim.x * 128;

    // A: zero voxel grid
    float4 z = make_float4(0.f, 0.f, 0.f, 0.f);
    for (int i = gtid; i < NV / 4; i += gstride) vox4[i] = z;

    // B: per-batch max of t (t>0 -> int ordering == float ordering)
    __shared__ int smax[BATCH];
    if (tid < BATCH) smax[tid] = 0;
    __syncthreads();
    for (int i = gtid; i < NEV; i += gstride) {
        float t = ev[i * 5 + 2];
        int b = (int)ev[i * 5 + 4];
        atomicMax(&smax[b], __float_as_int(t));
    }
    __syncthreads();
    if (tid < BATCH) atomicMax(&bmax_i[tid], smax[tid]);

    // C: table node `blk`
    __shared__ float h1s[100];
    __shared__ float red[128];
    float s = -1.f + 2.f * (float)blk / (float)TN;
    if (tid < 100) {
        float h = fmaf(s, W1[tid], b1[tid]);
        h1s[tid] = h > 0.f ? h : NEG_SLOPE * h;
    }
    __syncthreads();
    float acc = 0.f;
    if (tid < 100) {
        #pragma unroll 4
        for (int j = 0; j < 100; ++j) acc = fmaf(h1s[j], W2[j * 100 + tid], acc);
        acc += b2[tid];
        acc = acc > 0.f ? acc : NEG_SLOPE * acc;
        acc *= W3[tid];
    } 
    red[tid] = tid < 100 ? acc : 0.f;
    __syncthreads();
    for (int off = 64; off > 0; off >>= 1) {
        if (tid < off) red[tid] += red[tid + off];
        __syncthreads();
    }
    if (tid == 0) table[blk] = red[0] + b3[0];
}

// ---------------- kernel B: scatter events into voxel grid ----------------
// s_bin = tn - bin/8; node coord u = (s+1)*TN/2 = u0 - 128*bin (exact integer
// offset) -> one floorf + one frac shared by all 9 bins.
__global__ void scatter_kernel(const float* __restrict__ ev,
                               const int* __restrict__ bmax_i,
                               const float* __restrict__ table,
                               float* __restrict__ vox) {
    int i = blockIdx.x * blockDim.x + threadIdx.x;
    if (i >= NEV) return;
    float x = ev[i * 5 + 0];
    float y = ev[i * 5 + 1];
    float t = ev[i * 5 + 2];
    float p = ev[i * 5 + 3];
    int   b = (int)ev[i * 5 + 4];
    float tn = t / __int_as_float(bmax_i[b]);
    int base = (int)x + W_IN * (int)y + HW * C_BINS * (int)p + HW * C_BINS * 2 * b;
    float u0 = (tn + 1.f) * (0.5f * (float)TN);
    int k0 = (int)floorf(u0);
    float f = u0 - (float)k0;
    #pragma unroll
    for (int bin = 0; bin < C_BINS; ++bin) {
        int k = k0 - 128 * bin;                  // 128 = (1/8)*(TN/2), exact
        float fb = f;
        if (k >= TN) { k = TN - 1; fb = 1.f; }   // s == 1.0 exactly (the max event)
        if (k < 0)   { k = 0;      fb = 0.f; }   // cannot happen (s > -1), safety
        float t0 = table[k], t1 = table[k + 1];
        float g = fmaf(t1 - t0, fb, t0);
        int idx = base + HW * bin;
        idx = max(0, min(idx, NV - 1));
        atomicAdd(&vox[idx], tn * g);
    }
}

// ---------------- kernel C: letterbox fill + bilinear resize, LDS-staged ----
__global__ __launch_bounds__(256) void out_kernel2(const float* __restrict__ vox,
                                                   float* __restrict__ out) {
    int bc = blockIdx.x / 80;          // 0..143 plane (b*18 + ch)
    int ty = blockIdx.x % 80;          // 8-row tile within the 640-row image
    int oy0 = ty * 8;
    int tid = threadIdx.x;
    float4* dst = (float4*)(out + ((size_t)bc * IMG + oy0) * IMG);

    if (ty < 10 || ty >= 70) {         // letterbox bars (tile-aligned)
        float4 v = make_float4(114.f, 114.f, 114.f, 114.f);
        for (int g = tid; g < 1280; g += 256) dst[g] = v;
        return;
    }

    __shared__ float sm[5][W_IN];
    int ry0 = oy0 - 80;
    float sy0 = fmaf((float)ry0 + 0.5f, 0.375f, -0.5f);
    int ybase = (int)floorf(sy0);
    const float* plane = vox + (size_t)bc * HW;
    for (int idx = tid; idx < 5 * W_IN; idx += 256) {
        int r = idx / W_IN, c = idx - (idx / W_IN) * W_IN;
        int sr = min(max(ybase + r, 0), H_IN - 1);
        sm[r][c] = plane[sr * W_IN + c];
    }
    __syncthreads();

    for (int g = tid; g < 1280; g += 256) {
        int row = g / 160;
        int gx = g - row * 160;
        int ry = ry0 + row;
        float sy = fmaf((float)ry + 0.5f, 0.375f, -0.5f);
        int y0 = (int)floorf(sy);
        float wy = sy - (float)y0;
        int l1 = min(y0 + 1, H_IN - 1) - ybase;
        int l0 = max(y0, 0) - ybase;
        const float* r0 = sm[l0];
        const float* r1 = sm[l1];
        float res[4];
        #pragma unroll
        for (int q = 0; q < 4; ++q) {
            int ox = gx * 4 + q;
            float sx = fmaf((float)ox + 0.5f, 0.375f, -0.5f);
            int x0 = (int)floorf(sx);
            float wx = sx - (float)x0;
            int x1 = min(x0 + 1, W_IN - 1);
            x0 = max(x0, 0);
            float top = fmaf(r0[x1] - r0[x0], wx, r0[x0]);
            float bot = fmaf(r1[x1] - r1[x0], wx, r1[x0]);
            res[q] = fmaf(bot - top, wy, top);
        }
        dst[g] = make_float4(res[0], res[1], res[2], res[3]);
    }
}

extern "C" void kernel_launch(void* const* d_in, const int* in_sizes, int n_in,
                              void* d_out, int out_size, void* d_ws, size_t ws_size,
                              hipStream_t stream) {
    const float* ev = (const float*)d_in[0];
    const float* W1 = (const float*)d_in[1];
    const float* b1 = (const float*)d_in[2];
    const float* W2 = (const float*)d_in[3];
    const float* b2 = (const float*)d_in[4];
    const float* W3 = (const float*)d_in[5];
    const float* b3 = (const float*)d_in[6];
    float* out = (float*)d_out;

    char* ws = (char*)d_ws;
    int*    bmax_i = (int*)(ws + WS_BMAX_OFF);
    float*  table  = (float*)(ws + WS_TABLE_OFF);
    float*  vox    = (float*)(ws + WS_VOX_OFF);

    prep_kernel<<<TN + 1, 128, 0, stream>>>(ev, W1, b1, W2, b2, W3, b3,
                                            bmax_i, table, (float4*)vox);
    scatter_kernel<<<(NEV + 255) / 256, 256, 0, stream>>>(ev, bmax_i, table, vox);
    out_kernel2<<<144 * 80, 256, 0, stream>>>(vox, out);
}